// Round 2
// baseline (438.452 us; speedup 1.0000x reference)
//
#include <hip/hip_runtime.h>

#define VOCAB 50000
#define SEQ   200
#define NF4   (VOCAB / 4)   // 12500 float4 stores per row

// One block per batch row. Phase 1 zero-fills the row directly in global
// memory with float4 stores (the output is 99.6% zeros); phase 2 scatters
// the 200 token increments as f32 global atomics into the freshly-zeroed,
// L2-resident row. No LDS -> no occupancy cap (8 blocks/CU vs 3 for the
// old 50KB-LDS histogram version) and no ds_read/unpack chain on the
// store path: the write stream is pure global_store_dwordx4 of a zero reg.
//
// Correctness of phase1->phase2 ordering: __syncthreads() on CDNA drains
// vmcnt (all stores complete to L2) before any thread proceeds; atomics
// execute at the same XCD-local L2 the stores landed in, so the RMW sees
// the zeros. Duplicate indices within a row combine exactly via the
// atomic (counts <= 200, integers exact in f32).
__global__ __launch_bounds__(256) void MultihotEmbedding_16458314678493_kernel(
    const int* __restrict__ x, float* __restrict__ out) {
  const int row = blockIdx.x;
  float* __restrict__ orow = out + (size_t)row * VOCAB;

  // Phase 1: dense zero of this row (49 float4 stores per thread).
  float4* __restrict__ o4 = (float4*)orow;
  const float4 z = make_float4(0.f, 0.f, 0.f, 0.f);
  for (int i = threadIdx.x; i < NF4; i += 256) o4[i] = z;
  __syncthreads();

  // Phase 2: 200 scattered atomic increments into the L2-hot row.
  const int t = threadIdx.x;
  if (t < SEQ) {
    const int idx = x[row * SEQ + t];
    atomicAdd(orow + idx, 1.0f);
  }
}

extern "C" void kernel_launch(void* const* d_in, const int* in_sizes, int n_in,
                              void* d_out, int out_size, void* d_ws, size_t ws_size,
                              hipStream_t stream) {
  const int* x = (const int*)d_in[0];
  float* out = (float*)d_out;
  const int batch = in_sizes[0] / SEQ;  // 2048
  MultihotEmbedding_16458314678493_kernel<<<batch, 256, 0, stream>>>(x, out);
}